// Round 10
// baseline (318.834 us; speedup 1.0000x reference)
//
#include <hip/hip_runtime.h>
#include <math.h>

constexpr int NPGc  = 128;     // nodes per graph (layer 1)
constexpr int NG    = 512;     // graphs
constexpr int EPGc  = 2048;    // edges per graph
constexpr int ETOT  = 1048576; // total edges
constexpr int IND   = 11;
constexpr int HIDc  = 32;
constexpr int FD    = 128;     // HEADS*HID
constexpr int K1c   = 103;
constexpr int K2c   = 83;
constexpr int NN    = NG * NPGc;
constexpr int N2c   = NG * K1c;

__device__ __forceinline__ float lrelu(float x){ return fmaxf(x, 0.2f*x); }

// order-preserving float<->uint for atomicMax (max is order-invariant => exact)
__device__ __forceinline__ unsigned flipF(float f){
    unsigned u = __float_as_uint(f);
    return u ^ (unsigned)(((int)u >> 31) | 0x80000000);
}
__device__ __forceinline__ float unflipF(unsigned u){
    unsigned m = ((u >> 31) - 1u) | 0x80000000u;
    return __uint_as_float(u ^ m);
}

// ---- fold attention vectors through Wg: Ws[k][h] = sum_j Wg[k][h*32+j]*av[h*32+j]
template<int KIN>
__device__ void foldDev(const float* __restrict__ Wg, const float* __restrict__ avs,
                        const float* __restrict__ avd, float* __restrict__ S, float* __restrict__ D, int t)
{
    if (t < KIN * 4) {
        int k = t >> 2, h = t & 3;
        float s = 0.f, d = 0.f;
        for (int j = 0; j < HIDc; j++) {
            float w = Wg[k*FD + h*HIDc + j];
            s = fmaf(w, avs[h*HIDc + j], s);
            d = fmaf(w, avd[h*HIDc + j], d);
        }
        S[t] = s; D[t] = d;
    }
}

// ---- prep: blocks 0..511 build layer-1 CSR; blocks 512/513 do the folds ----
__global__ __launch_bounds__(256) void k_prep(const int* __restrict__ ei,
    const float* __restrict__ W1g, const float* __restrict__ s1, const float* __restrict__ d1,
    const float* __restrict__ W2g, const float* __restrict__ s2, const float* __restrict__ d2,
    int* __restrict__ csrOff, unsigned char* __restrict__ csrSB, unsigned char* __restrict__ csrDB,
    float* __restrict__ S1, float* __restrict__ D1, float* __restrict__ S2, float* __restrict__ D2)
{
    int b = blockIdx.x, t = threadIdx.x;
    if (b >= NG) {
        if (b == NG)     foldDev<IND>(W1g, s1, d1, S1, D1, t);
        else             foldDev<HIDc>(W2g, s2, d2, S2, D2, t);
        return;
    }
    int g = b;
    __shared__ int cnt[128], cur[128], offL[129];
    __shared__ unsigned char sbL[EPGc], dbL[EPGc];
    if (t < 128) cnt[t] = 0;
    __syncthreads();
    const int* dstG = ei + ETOT + g * EPGc;
    int dnv[8];
    #pragma unroll
    for (int q = 0; q < 8; q++) {
        int e = t + 256*q;
        dnv[q] = dstG[e] - g * NPGc;
        atomicAdd(&cnt[dnv[q]], 1);
    }
    __syncthreads();
    if (t < 64) {
        int c0 = cnt[2*t], c1 = cnt[2*t + 1], ps = c0 + c1, P = ps;
        #pragma unroll
        for (int dl = 1; dl < 64; dl <<= 1) { int v = __shfl_up(P, dl); if (t >= dl) P += v; }
        int E0 = P - ps;
        offL[2*t] = E0; offL[2*t + 1] = E0 + c0;
        cur[2*t]  = E0; cur[2*t + 1]  = E0 + c0;
        if (t == 63) offL[128] = P;
    }
    __syncthreads();
    #pragma unroll
    for (int q = 0; q < 8; q++) {
        int e = t + 256*q;
        int pos = atomicAdd(&cur[dnv[q]], 1);
        sbL[pos] = (unsigned char)(e >> 4);          // src is structural: e/16
        dbL[pos] = (unsigned char)dnv[q];
    }
    __syncthreads();
    if (t < 128) {
        ((int4*)(csrSB + (size_t)g * EPGc))[t] = ((const int4*)sbL)[t];
        ((int4*)(csrDB + (size_t)g * EPGc))[t] = ((const int4*)dbL)[t];
    }
    if (t <= NPGc) csrOff[g*132 + t] = offL[t];
}

// =====================================================================
// Fused layer (R9 body; ONLY change: per-head Wg/Wt slices + mLn in
// place of admL  =>  LDS < 54.6 KB  =>  3 blocks/CU) + same tails.
// =====================================================================
template<int NNODE, int KIN, int KEEP, bool FIRST>
__global__ __launch_bounds__(256, 4) void k_layer(
    const float* __restrict__ xin, const float* __restrict__ Wg,
    const float* __restrict__ WsS, const float* __restrict__ WsD,
    const float* __restrict__ bg,
    const float* __restrict__ Wt, const float* __restrict__ bt,
    const float* __restrict__ pw,
    const int* __restrict__ csrOff, const unsigned char* __restrict__ csrSB,
    const unsigned char* __restrict__ csrDB,
    const int* __restrict__ ei,                                   // FIRST: for csr2 tail
    int* __restrict__ csrOffW, unsigned char* __restrict__ sbW,   // FIRST: csr2 out
    unsigned char* __restrict__ dbW,
    float* __restrict__ xnew,
    float* __restrict__ gfeat, const float* __restrict__ gprev,
    const float* __restrict__ W1, const float* __restrict__ b1,   // !FIRST: MLP
    const float* __restrict__ W2, const float* __restrict__ b2,
    const float* __restrict__ W3, const float* __restrict__ b3,
    float* __restrict__ outp)
{
    constexpr int NP   = (NNODE + 3) & ~3;   // node count padded to mult of 4
    constexpr int NGRP = NP / 4;
    int g = blockIdx.x, t = threadIdx.x;

    __shared__ __align__(16) float xFT[KIN * NP];     // transposed input [k][n]
    __shared__ __align__(16) float WgsL[KIN * 32];    // per-head Wg column slice
    __shared__ __align__(16) float WtsL[1024];        // per-head Wt slice (32x32)
    __shared__ __align__(16) float xpL[NP * 36];      // proj / relu slice; later htL
    __shared__ float wEu[EPGc];                       // edge weights; later pool arrays / mlp h1+red
    __shared__ unsigned char sbL[EPGc], dbL[EPGc];
    __shared__ int offL[NNODE + 1 > 129 ? NNODE + 1 : 129];
    __shared__ float asL[NNODE], adL[NNODE], sfW[NNODE], sDi[NNODE];
    __shared__ unsigned maxU[NNODE];                  // reused in place as mLn
    __shared__ float WsSL[KIN * 4], WsDL[KIN * 4], bgL[FD], btL[HIDc];
    __shared__ float gvec[64];
    float* mLn = (float*)maxU;

    // ---- stage everything once ----
    {
        const float* xg = xin + (size_t)g * NNODE * KIN;
        for (int i = t; i < NNODE * KIN; i += 256) {
            int n = i / KIN, k = i - n * KIN;
            xFT[k * NP + n] = xg[i];
        }
        if constexpr (NP > NNODE) {
            for (int i = t; i < KIN * (NP - NNODE); i += 256) {
                int k = i / (NP - NNODE), n = NNODE + (i % (NP - NNODE));
                xFT[k * NP + n] = 0.f;                // zero pad cols -> pad rows stay 0
            }
        }
    }
    for (int i = t; i < KIN * 4; i += 256) { WsSL[i] = WsS[i]; WsDL[i] = WsD[i]; }
    if (t < FD) bgL[t] = bg[t];
    if (t < HIDc) btL[t] = bt[t];
    if (t <= NNODE) offL[t] = csrOff[g*132 + t];
    for (int i = t; i < EPGc / 16; i += 256) {
        ((int4*)sbL)[i] = ((const int4*)(csrSB + (size_t)g * EPGc))[i];
        ((int4*)dbL)[i] = ((const int4*)(csrDB + (size_t)g * EPGc))[i];
    }
    __syncthreads();
    const int EC = offL[NNODE];

    // W_t accumulators: thread owns (4 nodes, 4 out-channels); live across heads
    const int n4 = t >> 3, j4 = t & 7;
    float4 acc0, acc1, acc2, acc3;
    { float4 bi = make_float4(btL[j4*4], btL[j4*4+1], btL[j4*4+2], btL[j4*4+3]);
      acc0 = bi; acc1 = bi; acc2 = bi; acc3 = bi; }

    for (int h = 0; h < 4; h++) {
        __syncthreads();   // prev head's lin reads of xpL/WtsL done

        // stage this head's Wg column + Wt slice
        for (int i = t; i < KIN * 32; i += 256) WgsL[i] = Wg[(i >> 5)*FD + h*32 + (i & 31)];
        ((float4*)WtsL)[t] = ((const float4*)(Wt + h*1024))[t];
        __syncthreads();

        // proj: xpL[n][c] = sum_k xFT[k][n] * Wg[k][h*32+c]  (x as b128, 4 nodes/lane)
        for (int id = t; id < NGRP * 32; id += 256) {
            int grp = id >> 5, c = id & 31;
            float4 a = make_float4(0.f, 0.f, 0.f, 0.f);
            #pragma unroll
            for (int k = 0; k < KIN; k++) {
                float4 xv = *(const float4*)&xFT[k * NP + grp * 4];
                float w = WgsL[k*32 + c];
                a.x = fmaf(xv.x, w, a.x); a.y = fmaf(xv.y, w, a.y);
                a.z = fmaf(xv.z, w, a.z); a.w = fmaf(xv.w, w, a.w);
            }
            int nb = grp * 4;
            xpL[(nb+0)*36 + c] = a.x; xpL[(nb+1)*36 + c] = a.y;
            xpL[(nb+2)*36 + c] = a.z; xpL[(nb+3)*36 + c] = a.w;
        }
        // att dots via folded vectors; self seeds the max
        if (t < NNODE) {
            float s = 0.f, d = 0.f;
            #pragma unroll
            for (int k = 0; k < KIN; k++) {
                float v = xFT[k * NP + t];
                s = fmaf(v, WsSL[k*4 + h], s);
                d = fmaf(v, WsDL[k*4 + h], d);
            }
            asL[t] = s; adL[t] = d; maxU[t] = flipF(s);
        }
        __syncthreads();

        // slot-parallel exact per-dst max of as (lrelu monotone)
        for (int s = t; s < EC; s += 256)
            atomicMax(&maxU[dbL[s]], flipF(asL[sbL[s]]));
        __syncthreads();

        // node: m (in place over maxU), self weight
        if (t < NNODE) {
            float ad = adL[t];
            float m = lrelu(unflipF(maxU[t]) + ad);
            sfW[t] = expf(lrelu(asL[t] + ad) - m);
            mLn[t] = m;
        }
        __syncthreads();

        // slot-parallel edge weights (contiguous writes)
        for (int s = t; s < EC; s += 256) {
            int sb = sbL[s], db = dbL[s];
            wEu[s] = expf(lrelu(asL[sb] + adL[db]) - mLn[db]);
        }
        __syncthreads();

        // deterministic denominator in CSR order -> inverse
        if (t < NNODE) {
            float den = sfW[t];
            int lo = offL[t], hi = offL[t + 1];
            for (int s = lo; s < hi; s++) den += wEu[s];
            sDi[t] = 1.f / (den + 1e-16f);
        }
        __syncthreads();

        // aggregation (item = node, float4 chunk) into registers
        const float4* X4 = (const float4*)xpL;
        auto aggOne = [&](int p) -> float4 {
            int n = p >> 3, c4 = p & 7;
            float w0 = sfW[n];
            float4 v = X4[n*9 + c4];
            float4 a; a.x = w0*v.x; a.y = w0*v.y; a.z = w0*v.z; a.w = w0*v.w;
            int lo = offL[n], hi = offL[n + 1];
            for (int s = lo; s < hi; s++) {
                int sc = sbL[s]; float w = wEu[s];
                float4 u = X4[sc*9 + c4];
                a.x = fmaf(w, u.x, a.x); a.y = fmaf(w, u.y, a.y);
                a.z = fmaf(w, u.z, a.z); a.w = fmaf(w, u.w, a.w);
            }
            float inv = sDi[n];
            float4 r;
            r.x = fmaxf(fmaf(a.x, inv, bgL[h*32 + c4*4 + 0]), 0.f);
            r.y = fmaxf(fmaf(a.y, inv, bgL[h*32 + c4*4 + 1]), 0.f);
            r.z = fmaxf(fmaf(a.z, inv, bgL[h*32 + c4*4 + 2]), 0.f);
            r.w = fmaxf(fmaf(a.w, inv, bgL[h*32 + c4*4 + 3]), 0.f);
            return r;
        };
        float4 rv0 = aggOne(t);
        float4 rv1 = aggOne(t + 256);
        float4 rv2 = aggOne(t + 512);
        float4 rv3;
        if (t + 768 < NNODE * 8) rv3 = aggOne(t + 768);
        __syncthreads();   // all agg reads of xpL done

        // write relu slice back into xpL (in place)
        float4* X4w = (float4*)xpL;
        X4w[(t>>3)*9 + (t&7)] = rv0;
        { int p = t + 256; X4w[(p>>3)*9 + (p&7)] = rv1; }
        { int p = t + 512; X4w[(p>>3)*9 + (p&7)] = rv2; }
        if (t + 768 < NNODE * 8) { int p = t + 768; X4w[(p>>3)*9 + (p&7)] = rv3; }
        __syncthreads();

        // W_t accumulate: acc[n4..+3][j4*4..+3] += relu @ Wt[h*32..]
        if (n4 < NGRP) {
            int nb = n4 * 4;
            #pragma unroll 8
            for (int c = 0; c < 32; c++) {
                float4 w4 = *(const float4*)&WtsL[c*HIDc + j4*4];
                float r0 = xpL[(nb+0)*36 + c], r1 = xpL[(nb+1)*36 + c];
                float r2 = xpL[(nb+2)*36 + c], r3 = xpL[(nb+3)*36 + c];
                acc0.x = fmaf(r0, w4.x, acc0.x); acc0.y = fmaf(r0, w4.y, acc0.y);
                acc0.z = fmaf(r0, w4.z, acc0.z); acc0.w = fmaf(r0, w4.w, acc0.w);
                acc1.x = fmaf(r1, w4.x, acc1.x); acc1.y = fmaf(r1, w4.y, acc1.y);
                acc1.z = fmaf(r1, w4.z, acc1.z); acc1.w = fmaf(r1, w4.w, acc1.w);
                acc2.x = fmaf(r2, w4.x, acc2.x); acc2.y = fmaf(r2, w4.y, acc2.y);
                acc2.z = fmaf(r2, w4.z, acc2.z); acc2.w = fmaf(r2, w4.w, acc2.w);
                acc3.x = fmaf(r3, w4.x, acc3.x); acc3.y = fmaf(r3, w4.y, acc3.y);
                acc3.z = fmaf(r3, w4.z, acc3.z); acc3.w = fmaf(r3, w4.w, acc3.w);
            }
        }
    }
    __syncthreads();   // last lin reads done; xpL region becomes htL

    // ---- ht rows into LDS (row stride 33) ----
    float* htL = xpL;
    if (n4 < NGRP) {
        int nb = n4 * 4, jb = j4 * 4;
        float4 av[4] = {acc0, acc1, acc2, acc3};
        #pragma unroll
        for (int i = 0; i < 4; i++) {
            int n = nb + i;
            if (n < NNODE) {
                htL[n*33 + jb + 0] = av[i].x; htL[n*33 + jb + 1] = av[i].y;
                htL[n*33 + jb + 2] = av[i].z; htL[n*33 + jb + 3] = av[i].w;
            }
        }
    }
    __syncthreads();

    // ---- top-k pool + readout (score/rank alias wEu) ----
    float* scoreL = wEu;
    int*   rnkL   = (int*)(wEu + 128);
    float nrm; { float ss = 0.f; for (int k = 0; k < HIDc; k++) { float w = pw[k]; ss = fmaf(w, w, ss); } nrm = sqrtf(ss); }
    if (t < NNODE) {
        float dot = 0.f;
        for (int k = 0; k < HIDc; k++) dot = fmaf(htL[t*33 + k], pw[k], dot);
        scoreL[t] = tanhf(dot / nrm);
    }
    __syncthreads();
    if (t < NNODE) {
        float si = scoreL[t]; int rank = 0;
        for (int q = 0; q < NNODE; q++) {
            float sj = scoreL[q];
            rank += (sj > si || (sj == si && q < t)) ? 1 : 0;
        }
        rnkL[t] = (rank < KEEP) ? rank : -1;
    }
    __syncthreads();
    if constexpr (FIRST) {
        for (int p = t; p < NNODE * 32; p += 256) {
            int n = p >> 5, jj = p & 31;
            int rk = rnkL[n];
            if (rk >= 0) xnew[((size_t)g*KEEP + rk)*HIDc + jj] = htL[n*33 + jj] * scoreL[n];
        }
    }
    if (t < HIDc) {
        float mx = -INFINITY, sm = 0.f;
        for (int n = 0; n < NNODE; n++) {
            if (rnkL[n] >= 0) { float v = htL[n*33 + t] * scoreL[n]; mx = fmaxf(mx, v); sm += v; }
        }
        float mean = sm / (float)KEEP;
        if constexpr (FIRST) {
            gfeat[(size_t)g*64 + t]      = mx;
            gfeat[(size_t)g*64 + 32 + t] = mean;
        } else {
            gvec[t]      = gprev[(size_t)g*64 + t] + mx;
            gvec[32 + t] = gprev[(size_t)g*64 + 32 + t] + mean;
        }
    }

    if constexpr (FIRST) {
        // ---- tail: build layer-2 CSR from the in-LDS rank map ----
        __syncthreads();                    // rnkL stable; sbL/dbL/offL/maxU/sfW now dead
        int* cnt = (int*)maxU;
        int* cur = (int*)sfW;
        if (t < 128) cnt[t] = 0;
        __syncthreads();
        const int* dstG = ei + ETOT + g * EPGc;
        int snv[8], dnv[8];
        #pragma unroll
        for (int q = 0; q < 8; q++) {
            int e = t + 256*q;
            int s = rnkL[e >> 4], d = rnkL[dstG[e] - g * NPGc];
            bool ok = (s >= 0 && d >= 0);
            snv[q] = s; dnv[q] = ok ? d : -1;
            if (ok) atomicAdd(&cnt[d], 1);
        }
        __syncthreads();
        if (t < 64) {
            int c0 = cnt[2*t], c1 = cnt[2*t + 1], ps = c0 + c1, P = ps;
            #pragma unroll
            for (int dl = 1; dl < 64; dl <<= 1) { int v = __shfl_up(P, dl); if (t >= dl) P += v; }
            int E0 = P - ps;
            offL[2*t] = E0; offL[2*t + 1] = E0 + c0;
            cur[2*t]  = E0; cur[2*t + 1]  = E0 + c0;
            if (t == 63) offL[128] = P;
        }
        __syncthreads();
        #pragma unroll
        for (int q = 0; q < 8; q++) {
            if (dnv[q] >= 0) {
                int pos = atomicAdd(&cur[dnv[q]], 1);
                sbL[pos] = (unsigned char)snv[q];
                dbL[pos] = (unsigned char)dnv[q];
            }
        }
        __syncthreads();
        if (t < 128) {
            ((int4*)(sbW + (size_t)g * EPGc))[t] = ((const int4*)sbL)[t];
            ((int4*)(dbW + (size_t)g * EPGc))[t] = ((const int4*)dbL)[t];
        }
        if (t <= K1c) csrOffW[g*132 + t] = offL[t];
    } else {
        // ---- tail: fused MLP head gvec(64) -> 256 -> 1024 -> 1 ----
        __syncthreads();                    // gvec ready; wEu free
        float* h1L = wEu;
        float* red = wEu + 256;
        float a = b1[t];
        #pragma unroll 4
        for (int k = 0; k < 64; k++) a = fmaf(gvec[k], W1[k*256 + t], a);
        h1L[t] = fmaxf(a, 0.f);
        __syncthreads();
        float c0 = b2[t], c1 = b2[t + 256], c2 = b2[t + 512], c3 = b2[t + 768];
        const float* w2c = W2 + t;
        #pragma unroll 4
        for (int i = 0; i < 256; i++) {
            float hv = h1L[i];
            const float* wr = w2c + (size_t)i * 1024;
            c0 = fmaf(hv, wr[0],   c0);
            c1 = fmaf(hv, wr[256], c1);
            c2 = fmaf(hv, wr[512], c2);
            c3 = fmaf(hv, wr[768], c3);
        }
        float p = fmaf(fmaxf(c0, 0.f), W3[t],
                  fmaf(fmaxf(c1, 0.f), W3[t + 256],
                  fmaf(fmaxf(c2, 0.f), W3[t + 512],
                       fmaxf(c3, 0.f) * W3[t + 768])));
        red[t] = p;
        __syncthreads();
        for (int s = 128; s > 0; s >>= 1) { if (t < s) red[t] += red[t + s]; __syncthreads(); }
        if (t == 0) outp[g] = red[0] + b3[0];
    }
}

extern "C" void kernel_launch(void* const* d_in, const int* in_sizes, int n_in,
                              void* d_out, int out_size, void* d_ws, size_t ws_size,
                              hipStream_t stream)
{
    const float* x    = (const float*)d_in[0];
    const int*   ei   = (const int*)  d_in[1];
    const float* W_g1 = (const float*)d_in[4];
    const float* as1w = (const float*)d_in[5];
    const float* ad1w = (const float*)d_in[6];
    const float* b_g1 = (const float*)d_in[7];
    const float* W_t1 = (const float*)d_in[8];
    const float* b_t1 = (const float*)d_in[9];
    const float* pw1  = (const float*)d_in[10];
    const float* W_g2 = (const float*)d_in[11];
    const float* as2w = (const float*)d_in[12];
    const float* ad2w = (const float*)d_in[13];
    const float* b_g2 = (const float*)d_in[14];
    const float* W_t2 = (const float*)d_in[15];
    const float* b_t2 = (const float*)d_in[16];
    const float* pw2  = (const float*)d_in[17];
    const float* W_l1 = (const float*)d_in[18];
    const float* b_l1 = (const float*)d_in[19];
    const float* W_l2 = (const float*)d_in[20];
    const float* b_l2 = (const float*)d_in[21];
    const float* W_l3 = (const float*)d_in[22];
    const float* b_l3 = (const float*)d_in[23];
    float* out = (float*)d_out;

    char* ws = (char*)d_ws;
    size_t off = 0;
    auto alloc = [&](size_t bytes) -> void* {
        void* p = (void*)(ws + off);
        off += ((bytes + 255) / 256) * 256;
        return p;
    };
    float* x2    = (float*)alloc((size_t)N2c * HIDc * 4);
    float* g1    = (float*)alloc((size_t)NG * 64 * 4);
    float* wsS1  = (float*)alloc(64 * 4);
    float* wsD1  = (float*)alloc(64 * 4);
    float* wsS2  = (float*)alloc(128 * 4);
    float* wsD2  = (float*)alloc(128 * 4);
    int*   off1  = (int*)  alloc((size_t)NG * 132 * 4);
    unsigned char* sb1 = (unsigned char*)alloc((size_t)NG * EPGc);
    unsigned char* db1 = (unsigned char*)alloc((size_t)NG * EPGc);
    int*   off2  = (int*)  alloc((size_t)NG * 132 * 4);
    unsigned char* sb2 = (unsigned char*)alloc((size_t)NG * EPGc);
    unsigned char* db2 = (unsigned char*)alloc((size_t)NG * EPGc);

    k_prep<<<NG + 2, 256, 0, stream>>>(ei, W_g1, as1w, ad1w, W_g2, as2w, ad2w,
                                       off1, sb1, db1, wsS1, wsD1, wsS2, wsD2);

    k_layer<NPGc, IND, K1c, true><<<NG, 256, 0, stream>>>(
        x, W_g1, wsS1, wsD1, b_g1, W_t1, b_t1, pw1,
        off1, sb1, db1,
        ei, off2, sb2, db2,
        x2, g1, nullptr,
        nullptr, nullptr, nullptr, nullptr, nullptr, nullptr, nullptr);

    k_layer<K1c, HIDc, K2c, false><<<NG, 256, 0, stream>>>(
        x2, W_g2, wsS2, wsD2, b_g2, W_t2, b_t2, pw2,
        off2, sb2, db2,
        nullptr, nullptr, nullptr, nullptr,
        nullptr, nullptr, g1,
        W_l1, b_l1, W_l2, b_l2, W_l3, b_l3, out);
}

// Round 11
// 296.069 us; speedup vs baseline: 1.0769x; 1.0769x over previous
//
#include <hip/hip_runtime.h>
#include <math.h>

constexpr int NPGc  = 128;     // nodes per graph (layer 1)
constexpr int NG    = 512;     // graphs
constexpr int EPGc  = 2048;    // edges per graph
constexpr int ETOT  = 1048576; // total edges
constexpr int IND   = 11;
constexpr int HIDc  = 32;
constexpr int FD    = 128;     // HEADS*HID
constexpr int K1c   = 103;
constexpr int K2c   = 83;
constexpr int NN    = NG * NPGc;
constexpr int N2c   = NG * K1c;

__device__ __forceinline__ float lrelu(float x){ return fmaxf(x, 0.2f*x); }

// ---- fold attention vectors through Wg: Ws[k][h] = sum_j Wg[k][h*32+j]*av[h*32+j]
template<int KIN>
__device__ void foldDev(const float* __restrict__ Wg, const float* __restrict__ avs,
                        const float* __restrict__ avd, float* __restrict__ S, float* __restrict__ D, int t)
{
    if (t < KIN * 4) {
        int k = t >> 2, h = t & 3;
        float s = 0.f, d = 0.f;
        for (int j = 0; j < HIDc; j++) {
            float w = Wg[k*FD + h*HIDc + j];
            s = fmaf(w, avs[h*HIDc + j], s);
            d = fmaf(w, avd[h*HIDc + j], d);
        }
        S[t] = s; D[t] = d;
    }
}

// ---- prep: blocks 0..511 build layer-1 CSR (off+src only); blocks 512/513 folds ----
__global__ __launch_bounds__(256) void k_prep(const int* __restrict__ ei,
    const float* __restrict__ W1g, const float* __restrict__ s1, const float* __restrict__ d1,
    const float* __restrict__ W2g, const float* __restrict__ s2, const float* __restrict__ d2,
    int* __restrict__ csrOff, unsigned char* __restrict__ csrSB,
    float* __restrict__ S1, float* __restrict__ D1, float* __restrict__ S2, float* __restrict__ D2)
{
    int b = blockIdx.x, t = threadIdx.x;
    if (b >= NG) {
        if (b == NG)     foldDev<IND>(W1g, s1, d1, S1, D1, t);
        else             foldDev<HIDc>(W2g, s2, d2, S2, D2, t);
        return;
    }
    int g = b;
    __shared__ int cnt[128], cur[128], offL[129];
    __shared__ unsigned char sbL[EPGc];
    if (t < 128) cnt[t] = 0;
    __syncthreads();
    const int* dstG = ei + ETOT + g * EPGc;
    int dnv[8];
    #pragma unroll
    for (int q = 0; q < 8; q++) {
        int e = t + 256*q;
        dnv[q] = dstG[e] - g * NPGc;
        atomicAdd(&cnt[dnv[q]], 1);
    }
    __syncthreads();
    if (t < 64) {
        int c0 = cnt[2*t], c1 = cnt[2*t + 1], ps = c0 + c1, P = ps;
        #pragma unroll
        for (int dl = 1; dl < 64; dl <<= 1) { int v = __shfl_up(P, dl); if (t >= dl) P += v; }
        int E0 = P - ps;
        offL[2*t] = E0; offL[2*t + 1] = E0 + c0;
        cur[2*t]  = E0; cur[2*t + 1]  = E0 + c0;
        if (t == 63) offL[128] = P;
    }
    __syncthreads();
    #pragma unroll
    for (int q = 0; q < 8; q++) {
        int e = t + 256*q;
        int pos = atomicAdd(&cur[dnv[q]], 1);
        sbL[pos] = (unsigned char)(e >> 4);          // src is structural: e/16
    }
    __syncthreads();
    if (t < 128) ((int4*)(csrSB + (size_t)g * EPGc))[t] = ((const int4*)sbL)[t];
    if (t <= NPGc) csrOff[g*132 + t] = offL[t];
}

// ---- GAT, one block per (graph, head): R6-measured body + Wt-partial tail ----
// writes htp[((g*NNODE + n)*4 + h)*32 + j]  (pure partial, no bias — summed in linpool)
template<int NNODE, int KIN>
__global__ __launch_bounds__(256) void k_gat(
    const float* __restrict__ xin, const float* __restrict__ Wg,
    const float* __restrict__ WsS, const float* __restrict__ WsD,
    const int* __restrict__ csrOff, const unsigned char* __restrict__ csrSB,
    const float* __restrict__ bias, const float* __restrict__ Wt,
    float* __restrict__ htp)
{
    int g = blockIdx.x, h = blockIdx.y, t = threadIdx.x;
    constexpr int UN = (NNODE*KIN > EPGc ? NNODE*KIN : EPGc);
    __shared__ __align__(16) float xpL[NNODE * 36];   // pad 36: conflict-free octet b128 gather
    __shared__ __align__(16) float uni[UN];           // phase<=1: xF staged input; phase>=2: wE
    __shared__ __align__(16) unsigned char sbL[EPGc];
    __shared__ float asL[NNODE], adL[NNODE], sfW[NNODE], sDen[NNODE];
    __shared__ int offL[NNODE + 1];
    __shared__ float WL[KIN * 32];
    __shared__ float WsSL[KIN], WsDL[KIN], bL[32];
    __shared__ __align__(16) float WtsL[1024];        // this head's Wt slice (32x32)

    float* xF  = uni;
    float* wEL = uni;

    // ---- phase 0: stage x slice, weights, CSR, Wt slice ----
    {
        const float* xg = xin + (size_t)g * NNODE * KIN;
        if constexpr ((KIN & 3) == 0) {
            for (int i = t; i < NNODE * (KIN/4); i += 256)
                ((float4*)xF)[i] = ((const float4*)xg)[i];
        } else {
            for (int i = t; i < NNODE * KIN; i += 256) xF[i] = xg[i];
        }
    }
    for (int i = t; i < KIN * 32; i += 256) { int k = i >> 5, c = i & 31; WL[i] = Wg[k*FD + h*32 + c]; }
    if (t < KIN) { WsSL[t] = WsS[t*4 + h]; WsDL[t] = WsD[t*4 + h]; }
    if (t < 32) bL[t] = bias[h*32 + t];
    if (t <= NNODE) offL[t] = csrOff[g*132 + t];
    if (t < 128) ((int4*)sbL)[t] = ((const int4*)(csrSB + (size_t)g * EPGc))[t];
    ((float4*)WtsL)[t] = ((const float4*)(Wt + h*1024))[t];
    __syncthreads();

    // ---- phase 1: xp = xF @ WL -> xpL ; as/ad from folded vectors ----
    for (int p = t; p < NNODE * 32; p += 256) {
        int n = p >> 5, c = p & 31;
        const float* xr = xF + n * KIN;
        float acc = 0.f;
        #pragma unroll
        for (int k = 0; k < KIN; k++) acc = fmaf(xr[k], WL[k*32 + c], acc);
        xpL[n*36 + c] = acc;
    }
    if (t < NNODE) {
        const float* xr = xF + t * KIN;
        float s = 0.f, d = 0.f;
        #pragma unroll
        for (int k = 0; k < KIN; k++) { float v = xr[k]; s = fmaf(v, WsSL[k], s); d = fmaf(v, WsDL[k], d); }
        asL[t] = s; adL[t] = d;
    }
    __syncthreads();

    // ---- phase 2: per-node segment max (lrelu monotone => exact), wE, denominator ----
    if (t < NNODE) {
        float as_n = asL[t], adn = adL[t];
        int lo = offL[t], hi = offL[t + 1];
        float mx = as_n;                                 // self-loop seeds max
        for (int i = lo; i < hi; i++) mx = fmaxf(mx, asL[sbL[i]]);
        float m = lrelu(mx + adn);
        float ws = expf(lrelu(as_n + adn) - m);
        float den = ws;
        for (int i = lo; i < hi; i++) {
            float w = expf(lrelu(asL[sbL[i]] + adn) - m);
            wEL[i] = w; den += w;
        }
        sfW[t] = ws; sDen[t] = den;
    }
    __syncthreads();

    // ---- phase 3: aggregation into registers, relu write-back, Wt-partial tail ----
    const float4* X4 = (const float4*)xpL;
    float4 rv[4];
    #pragma unroll
    for (int r = 0; r < 4; r++) {
        int p = t + r*256;
        if (p < NNODE * 8) {
            int n = p >> 3, c4 = p & 7;
            float w0 = sfW[n];
            float4 v = X4[n*9 + c4];
            float4 a; a.x = w0*v.x; a.y = w0*v.y; a.z = w0*v.z; a.w = w0*v.w;
            int lo = offL[n], hi = offL[n + 1];
            for (int s = lo; s < hi; s++) {
                int sc = sbL[s]; float w = wEL[s];
                float4 u = X4[sc*9 + c4];
                a.x = fmaf(w, u.x, a.x); a.y = fmaf(w, u.y, a.y);
                a.z = fmaf(w, u.z, a.z); a.w = fmaf(w, u.w, a.w);
            }
            float inv = 1.f / (sDen[n] + 1e-16f);
            rv[r].x = fmaxf(fmaf(a.x, inv, bL[c4*4 + 0]), 0.f);
            rv[r].y = fmaxf(fmaf(a.y, inv, bL[c4*4 + 1]), 0.f);
            rv[r].z = fmaxf(fmaf(a.z, inv, bL[c4*4 + 2]), 0.f);
            rv[r].w = fmaxf(fmaf(a.w, inv, bL[c4*4 + 3]), 0.f);
        }
    }
    __syncthreads();   // all agg reads of xpL done
    {
        float4* X4w = (float4*)xpL;
        #pragma unroll
        for (int r = 0; r < 4; r++) {
            int p = t + r*256;
            if (p < NNODE * 8) X4w[(p>>3)*9 + (p&7)] = rv[r];
        }
    }
    __syncthreads();

    // Wt-partial: thread owns nodes {n0, n0+32, n0+64, n0+96} x channel-quad j4
    const int n0 = t >> 3, j4 = t & 7;
    float4 a0 = make_float4(0,0,0,0), a1 = a0, a2 = a0, a3 = a0;
    #pragma unroll 8
    for (int c = 0; c < 32; c++) {
        float4 w4 = *(const float4*)&WtsL[c*HIDc + j4*4];
        float r0 = xpL[n0*36 + c];
        a0.x = fmaf(r0, w4.x, a0.x); a0.y = fmaf(r0, w4.y, a0.y);
        a0.z = fmaf(r0, w4.z, a0.z); a0.w = fmaf(r0, w4.w, a0.w);
        if (n0 + 32 < NNODE) {
            float r1 = xpL[(n0+32)*36 + c];
            a1.x = fmaf(r1, w4.x, a1.x); a1.y = fmaf(r1, w4.y, a1.y);
            a1.z = fmaf(r1, w4.z, a1.z); a1.w = fmaf(r1, w4.w, a1.w);
        }
        if (n0 + 64 < NNODE) {
            float r2 = xpL[(n0+64)*36 + c];
            a2.x = fmaf(r2, w4.x, a2.x); a2.y = fmaf(r2, w4.y, a2.y);
            a2.z = fmaf(r2, w4.z, a2.z); a2.w = fmaf(r2, w4.w, a2.w);
        }
        if (n0 + 96 < NNODE) {
            float r3 = xpL[(n0+96)*36 + c];
            a3.x = fmaf(r3, w4.x, a3.x); a3.y = fmaf(r3, w4.y, a3.y);
            a3.z = fmaf(r3, w4.z, a3.z); a3.w = fmaf(r3, w4.w, a3.w);
        }
    }
    {
        size_t base = ((size_t)(g * NNODE + n0) * 4 + h) * 32 + j4 * 4;
        *(float4*)(htp + base) = a0;
        if (n0 + 32 < NNODE) *(float4*)(htp + base + (size_t)32*128) = a1;
        if (n0 + 64 < NNODE) *(float4*)(htp + base + (size_t)64*128) = a2;
        if (n0 + 96 < NNODE) *(float4*)(htp + base + (size_t)96*128) = a3;
    }
}

// ---- linpool: ht = bt + sum of 4 head partials; pool + readout;
//      FIRST: xnew + layer-2 CSR build;  !FIRST: fused MLP head ----
template<int NIN, int KEEP, bool FIRST>
__global__ __launch_bounds__(256) void k_linpool(
    const float* __restrict__ htp, const float* __restrict__ bt, const float* __restrict__ pw,
    float* __restrict__ xnew, const int* __restrict__ ei,
    int* __restrict__ csrOffW, unsigned char* __restrict__ sbW,
    float* __restrict__ gfeat, const float* __restrict__ gprev,
    const float* __restrict__ W1, const float* __restrict__ b1,
    const float* __restrict__ W2, const float* __restrict__ b2,
    const float* __restrict__ W3, const float* __restrict__ b3,
    float* __restrict__ outp)
{
    int g = blockIdx.x, t = threadIdx.x;
    __shared__ float htL[NIN * 33];
    __shared__ float scoreL[NIN];
    __shared__ int rnkL[NIN];
    __shared__ int cnt[128], cur[128], offL[129];
    __shared__ unsigned char sbL[EPGc];
    __shared__ float gvec[64];
    __shared__ float h1L[256], red[256];

    // ---- ht assembly: bt + h0 + h1 + h2 + h3 (deterministic) ----
    for (int p = t; p < NIN * 8; p += 256) {
        int n = p >> 3, q = p & 7;
        const float4* row = (const float4*)(htp + (size_t)(g * NIN + n) * 128);
        float4 s = ((const float4*)bt)[q];
        float4 p0 = row[q], p1 = row[8 + q], p2 = row[16 + q], p3 = row[24 + q];
        s.x += p0.x; s.y += p0.y; s.z += p0.z; s.w += p0.w;
        s.x += p1.x; s.y += p1.y; s.z += p1.z; s.w += p1.w;
        s.x += p2.x; s.y += p2.y; s.z += p2.z; s.w += p2.w;
        s.x += p3.x; s.y += p3.y; s.z += p3.z; s.w += p3.w;
        float* d = htL + n*33 + q*4;
        d[0] = s.x; d[1] = s.y; d[2] = s.z; d[3] = s.w;
    }
    __syncthreads();

    // ---- score / rank ----
    float nrm; { float ss = 0.f; for (int k = 0; k < HIDc; k++) { float w = pw[k]; ss = fmaf(w, w, ss); } nrm = sqrtf(ss); }
    if (t < NIN) {
        float dot = 0.f;
        for (int k = 0; k < HIDc; k++) dot = fmaf(htL[t*33 + k], pw[k], dot);
        scoreL[t] = tanhf(dot / nrm);
    }
    __syncthreads();
    if (t < NIN) {
        float si = scoreL[t]; int rank = 0;
        for (int q = 0; q < NIN; q++) {
            float sj = scoreL[q];
            rank += (sj > si || (sj == si && q < t)) ? 1 : 0;
        }
        rnkL[t] = (rank < KEEP) ? rank : -1;
    }
    __syncthreads();
    if constexpr (FIRST) {
        for (int p = t; p < NIN * 32; p += 256) {
            int n = p >> 5, jj = p & 31;
            int rk = rnkL[n];
            if (rk >= 0) xnew[((size_t)g*KEEP + rk)*HIDc + jj] = htL[n*33 + jj] * scoreL[n];
        }
    }
    if (t < HIDc) {
        float mx = -INFINITY, sm = 0.f;
        for (int n = 0; n < NIN; n++) {
            if (rnkL[n] >= 0) { float v = htL[n*33 + t] * scoreL[n]; mx = fmaxf(mx, v); sm += v; }
        }
        float mean = sm / (float)KEEP;
        if constexpr (FIRST) {
            gfeat[(size_t)g*64 + t]      = mx;
            gfeat[(size_t)g*64 + 32 + t] = mean;
        } else {
            gvec[t]      = gprev[(size_t)g*64 + t] + mx;
            gvec[32 + t] = gprev[(size_t)g*64 + 32 + t] + mean;
        }
    }

    if constexpr (FIRST) {
        // ---- tail: build layer-2 CSR from the in-LDS rank map ----
        __syncthreads();
        if (t < 128) cnt[t] = 0;
        __syncthreads();
        const int* dstG = ei + ETOT + g * EPGc;
        int snv[8], dnv[8];
        #pragma unroll
        for (int q = 0; q < 8; q++) {
            int e = t + 256*q;
            int s = rnkL[e >> 4], d = rnkL[dstG[e] - g * NPGc];
            bool ok = (s >= 0 && d >= 0);
            snv[q] = s; dnv[q] = ok ? d : -1;
            if (ok) atomicAdd(&cnt[d], 1);
        }
        __syncthreads();
        if (t < 64) {
            int c0 = cnt[2*t], c1 = cnt[2*t + 1], ps = c0 + c1, P = ps;
            #pragma unroll
            for (int dl = 1; dl < 64; dl <<= 1) { int v = __shfl_up(P, dl); if (t >= dl) P += v; }
            int E0 = P - ps;
            offL[2*t] = E0; offL[2*t + 1] = E0 + c0;
            cur[2*t]  = E0; cur[2*t + 1]  = E0 + c0;
            if (t == 63) offL[128] = P;
        }
        __syncthreads();
        #pragma unroll
        for (int q = 0; q < 8; q++) {
            if (dnv[q] >= 0) {
                int pos = atomicAdd(&cur[dnv[q]], 1);
                sbL[pos] = (unsigned char)snv[q];
            }
        }
        __syncthreads();
        if (t < 128) ((int4*)(sbW + (size_t)g * EPGc))[t] = ((const int4*)sbL)[t];
        if (t <= K1c) csrOffW[g*132 + t] = offL[t];
    } else {
        // ---- tail: fused MLP head gvec(64) -> 256 -> 1024 -> 1 ----
        __syncthreads();
        float a = b1[t];
        #pragma unroll 4
        for (int k = 0; k < 64; k++) a = fmaf(gvec[k], W1[k*256 + t], a);
        h1L[t] = fmaxf(a, 0.f);
        __syncthreads();
        float c0 = b2[t], c1 = b2[t + 256], c2 = b2[t + 512], c3 = b2[t + 768];
        const float* w2c = W2 + t;
        #pragma unroll 4
        for (int i = 0; i < 256; i++) {
            float hv = h1L[i];
            const float* wr = w2c + (size_t)i * 1024;
            c0 = fmaf(hv, wr[0],   c0);
            c1 = fmaf(hv, wr[256], c1);
            c2 = fmaf(hv, wr[512], c2);
            c3 = fmaf(hv, wr[768], c3);
        }
        float p = fmaf(fmaxf(c0, 0.f), W3[t],
                  fmaf(fmaxf(c1, 0.f), W3[t + 256],
                  fmaf(fmaxf(c2, 0.f), W3[t + 512],
                       fmaxf(c3, 0.f) * W3[t + 768])));
        red[t] = p;
        __syncthreads();
        for (int s = 128; s > 0; s >>= 1) { if (t < s) red[t] += red[t + s]; __syncthreads(); }
        if (t == 0) outp[g] = red[0] + b3[0];
    }
}

extern "C" void kernel_launch(void* const* d_in, const int* in_sizes, int n_in,
                              void* d_out, int out_size, void* d_ws, size_t ws_size,
                              hipStream_t stream)
{
    const float* x    = (const float*)d_in[0];
    const int*   ei   = (const int*)  d_in[1];
    const float* W_g1 = (const float*)d_in[4];
    const float* as1w = (const float*)d_in[5];
    const float* ad1w = (const float*)d_in[6];
    const float* b_g1 = (const float*)d_in[7];
    const float* W_t1 = (const float*)d_in[8];
    const float* b_t1 = (const float*)d_in[9];
    const float* pw1  = (const float*)d_in[10];
    const float* W_g2 = (const float*)d_in[11];
    const float* as2w = (const float*)d_in[12];
    const float* ad2w = (const float*)d_in[13];
    const float* b_g2 = (const float*)d_in[14];
    const float* W_t2 = (const float*)d_in[15];
    const float* b_t2 = (const float*)d_in[16];
    const float* pw2  = (const float*)d_in[17];
    const float* W_l1 = (const float*)d_in[18];
    const float* b_l1 = (const float*)d_in[19];
    const float* W_l2 = (const float*)d_in[20];
    const float* b_l2 = (const float*)d_in[21];
    const float* W_l3 = (const float*)d_in[22];
    const float* b_l3 = (const float*)d_in[23];
    float* out = (float*)d_out;

    char* ws = (char*)d_ws;
    size_t off = 0;
    auto alloc = [&](size_t bytes) -> void* {
        void* p = (void*)(ws + off);
        off += ((bytes + 255) / 256) * 256;
        return p;
    };
    float* htp1  = (float*)alloc((size_t)NN * 128 * 4);   // per-head Wt partials, layer 1
    float* htp2  = (float*)alloc((size_t)N2c * 128 * 4);  // layer 2
    float* x2    = (float*)alloc((size_t)N2c * HIDc * 4);
    float* g1    = (float*)alloc((size_t)NG * 64 * 4);
    float* wsS1  = (float*)alloc(64 * 4);
    float* wsD1  = (float*)alloc(64 * 4);
    float* wsS2  = (float*)alloc(128 * 4);
    float* wsD2  = (float*)alloc(128 * 4);
    int*   off1  = (int*)  alloc((size_t)NG * 132 * 4);
    unsigned char* sb1 = (unsigned char*)alloc((size_t)NG * EPGc);
    int*   off2  = (int*)  alloc((size_t)NG * 132 * 4);
    unsigned char* sb2 = (unsigned char*)alloc((size_t)NG * EPGc);

    k_prep<<<NG + 2, 256, 0, stream>>>(ei, W_g1, as1w, ad1w, W_g2, as2w, ad2w,
                                       off1, sb1, wsS1, wsD1, wsS2, wsD2);

    k_gat<NPGc, IND><<<dim3(NG, 4), 256, 0, stream>>>(
        x, W_g1, wsS1, wsD1, off1, sb1, b_g1, W_t1, htp1);

    k_linpool<NPGc, K1c, true><<<NG, 256, 0, stream>>>(
        htp1, b_t1, pw1, x2, ei, off2, sb2, g1, nullptr,
        nullptr, nullptr, nullptr, nullptr, nullptr, nullptr, nullptr);

    k_gat<K1c, HIDc><<<dim3(NG, 4), 256, 0, stream>>>(
        x2, W_g2, wsS2, wsD2, off2, sb2, b_g2, W_t2, htp2);

    k_linpool<K1c, K2c, false><<<NG, 256, 0, stream>>>(
        htp2, b_t2, pw2, nullptr, nullptr, nullptr, nullptr, nullptr, g1,
        W_l1, b_l1, W_l2, b_l2, W_l3, b_l3, out);
}